// Round 7
// baseline (201.882 us; speedup 1.0000x reference)
//
#include <hip/hip_runtime.h>
#include <hip/hip_bf16.h>
#include <math.h>

#define T_TOK 2048
#define H_DIM 2048
#define E_EXP 16
#define I_DIM 512
#define TWO_I 1024
#define ROUTED_SCALE 1.5f
#define SWIGLU_LIMIT 7.0f

#define BM 128
#define KC 32
#define MAX_TILES 48

typedef __attribute__((ext_vector_type(8))) short bf16x8;
typedef __attribute__((ext_vector_type(4))) float f32x4;
typedef unsigned short u16;

__device__ inline u16 f2bf(float f) {
    return __builtin_bit_cast(u16, __float2bfloat16(f));
}
__device__ inline ushort4 pack4(float4 a) {
    ushort4 v;
    v.x = f2bf(a.x); v.y = f2bf(a.y); v.z = f2bf(a.z); v.w = f2bf(a.w);
    return v;
}
__device__ inline bf16x8 cvt8(f32x4 a, f32x4 b) {
    bf16x8 v;
    v[0] = (short)f2bf(a[0]); v[1] = (short)f2bf(a[1]);
    v[2] = (short)f2bf(a[2]); v[3] = (short)f2bf(a[3]);
    v[4] = (short)f2bf(b[0]); v[5] = (short)f2bf(b[1]);
    v[6] = (short)f2bf(b[2]); v[7] = (short)f2bf(b[3]);
    return v;
}

// async 16B/lane global->LDS DMA (1 KB per wave instruction)
__device__ inline void gload16(const u16* g, u16* l) {
    __builtin_amdgcn_global_load_lds(
        (const __attribute__((address_space(1))) void*)(g),
        (__attribute__((address_space(3))) void*)(l), 16, 0, 0);
}
__device__ inline void gload16f(const float* g, float* l) {
    __builtin_amdgcn_global_load_lds(
        (const __attribute__((address_space(1))) void*)(g),
        (__attribute__((address_space(3))) void*)(l), 16, 0, 0);
}

#define VM_WAIT(n) asm volatile("s_waitcnt vmcnt(" #n ")" ::: "memory")
#define LGKM0()    asm volatile("s_waitcnt lgkmcnt(0)" ::: "memory")
#define SBAR()     asm volatile("s_barrier" ::: "memory")
#define SCHED0()   __builtin_amdgcn_sched_barrier(0)

// ---------------- router: one wave per token; also emits hs in bf16 ----------------
__global__ __launch_bounds__(256) void router_kernel(
    const float* __restrict__ hs, const float* __restrict__ gw,
    const float* __restrict__ bias, int* cnt, int* tok_list, float* w_list,
    u16* __restrict__ hs_bf)
{
    int wave = threadIdx.x >> 6;
    int lane = threadIdx.x & 63;
    int t = blockIdx.x * 4 + wave;
    if (t >= T_TOK) return;
    const float* x = hs + (size_t)t * H_DIM;

    float acc[E_EXP];
#pragma unroll
    for (int e = 0; e < E_EXP; ++e) acc[e] = 0.f;

#pragma unroll 2
    for (int c = 0; c < 8; ++c) {
        int col = c * 256 + lane * 4;
        float4 xv = *(const float4*)(x + col);
        *(ushort4*)(hs_bf + (size_t)t * H_DIM + col) = pack4(xv);
#pragma unroll
        for (int e = 0; e < E_EXP; ++e) {
            float4 gv = *(const float4*)(gw + (size_t)e * H_DIM + col);
            acc[e] = fmaf(xv.x, gv.x, acc[e]);
            acc[e] = fmaf(xv.y, gv.y, acc[e]);
            acc[e] = fmaf(xv.z, gv.z, acc[e]);
            acc[e] = fmaf(xv.w, gv.w, acc[e]);
        }
    }
#pragma unroll
    for (int e = 0; e < E_EXP; ++e) {
        for (int m = 32; m >= 1; m >>= 1)
            acc[e] += __shfl_xor(acc[e], m, 64);
    }
    if (lane == 0) {
        float sc[E_EXP], bsc[E_EXP];
#pragma unroll
        for (int e = 0; e < E_EXP; ++e) {
            sc[e] = 1.f / (1.f + expf(-acc[e]));
            bsc[e] = sc[e] + bias[e];
        }
        int e0 = 0; float b0 = bsc[0];
#pragma unroll
        for (int e = 1; e < E_EXP; ++e) if (bsc[e] > b0) { b0 = bsc[e]; e0 = e; }
        int e1 = -1; float b1 = -1e30f;
#pragma unroll
        for (int e = 0; e < E_EXP; ++e) {
            if (e == e0) continue;
            if (bsc[e] > b1) { b1 = bsc[e]; e1 = e; }
        }
        float s0 = sc[e0], s1 = sc[e1];
        float inv = ROUTED_SCALE / (s0 + s1);
        int p0 = atomicAdd(&cnt[e0], 1);
        tok_list[e0 * T_TOK + p0] = t;
        w_list[e0 * T_TOK + p0] = s0 * inv;
        int p1 = atomicAdd(&cnt[e1], 1);
        tok_list[e1 * T_TOK + p1] = t;
        w_list[e1 * T_TOK + p1] = s1 * inv;
    }
}

// ---------------- fused: compact assignments + tile descriptors (BM=128) ----------------
__global__ void scatter_build(const int* __restrict__ cnt,
    const int* __restrict__ tok_list, const float* __restrict__ w_list,
    int* A_tok, float* A_w, int* tile_e, int* tile_r0)
{
    int c[E_EXP], offs[E_EXP + 1];
    offs[0] = 0;
#pragma unroll
    for (int e = 0; e < E_EXP; ++e) {
        c[e] = cnt[e];
        offs[e + 1] = offs[e] + ((c[e] + BM - 1) & ~(BM - 1));
    }
    int idx = blockIdx.x * 256 + threadIdx.x;
    int e = idx >> 11;
    int pos = idx & (T_TOK - 1);
    int ce = c[e];
    int pe = (ce + BM - 1) & ~(BM - 1);
    if (pos < ce) {
        A_tok[offs[e] + pos] = tok_list[idx];
        A_w[offs[e] + pos] = w_list[idx];
    } else if (pos < pe) {
        A_tok[offs[e] + pos] = -1;
        A_w[offs[e] + pos] = 0.f;
    }
    if (idx == 0) {
        int nt = 0;
        for (int ee = 0; ee < E_EXP; ++ee) {
            int ntile = (c[ee] + BM - 1) >> 7;
            for (int j = 0; j < ntile; ++j) {
                tile_e[nt] = ee;
                tile_r0[nt] = offs[ee] + j * BM;
                ++nt;
            }
        }
        for (; nt < MAX_TILES; ++nt) tile_e[nt] = -1;
    }
}

// ---------------- GEMM1: all-gload_lds, counted-vmcnt pipeline ----------------
// X bf16 [128x32] + w13 fp32 [64G+64U x32] per K-step; cvt on LDS read.
__global__ __launch_bounds__(256, 3) void gemm1_act(
    const u16* __restrict__ hs_bf, const float* __restrict__ w13,
    const int* __restrict__ A_tok, const int* __restrict__ tile_e,
    const int* __restrict__ tile_r0, u16* __restrict__ act)
{
    int b = blockIdx.x;
    int id = (b & 7) * MAX_TILES + (b >> 3);   // 384 = 8*48; XCD x owns y-stripe x
    int tile = id % MAX_TILES;
    int y = id / MAX_TILES;                    // 0..7
    int e = tile_e[tile];
    if (e < 0) return;
    int row0 = tile_r0[tile];
    int i0 = y * 64;
    int tid = threadIdx.x;

    __shared__ u16  Xs[2][4096];   // 128 rows x 32 bf16
    __shared__ float Gs[2][2048];  // 64 rows x 32 fp32
    __shared__ float Us[2][2048];

    const int l = tid & 63, w = tid >> 6;

    // ---- staging sources (per-lane pre-swizzled) ----
    // X: instr j covers rows w*32+j*16+(l>>2), LDS granule l&3 holds src granule (l&3)^((l>>3)&3)
    const u16* sX[2]; int dX[2];
#pragma unroll
    for (int j = 0; j < 2; ++j) {
        int row = w * 32 + j * 16 + (l >> 2);
        int tk = A_tok[row0 + row]; if (tk < 0) tk = 0;
        int sg = (l & 3) ^ ((l >> 3) & 3);
        sX[j] = hs_bf + (size_t)tk * H_DIM + sg * 8;
        dX[j] = (w * 32 + j * 16) * 32;
    }
    // W: instr j covers rows w*16+j*8+(l>>3), LDS granule l&7 holds src granule (l&7)^(l>>3)
    const float* sG[2]; const float* sU[2]; int dW[2];
#pragma unroll
    for (int j = 0; j < 2; ++j) {
        int row = w * 16 + j * 8 + (l >> 3);
        int sg = (l & 7) ^ (l >> 3);
        sG[j] = w13 + ((size_t)e * TWO_I + i0 + row) * H_DIM + sg * 4;
        sU[j] = sG[j] + (size_t)I_DIM * H_DIM;
        dW[j] = (w * 16 + j * 8) * 32;
    }

#define G1_ISSUE(bb, t) do { int ko = (t) * KC; \
    gload16(sX[0] + ko, &Xs[bb][dX[0]]);  gload16(sX[1] + ko, &Xs[bb][dX[1]]); \
    gload16f(sG[0] + ko, &Gs[bb][dW[0]]); gload16f(sG[1] + ko, &Gs[bb][dW[1]]); \
    gload16f(sU[0] + ko, &Us[bb][dW[0]]); gload16f(sU[1] + ko, &Us[bb][dW[1]]); \
    SCHED0(); } while (0)

    // ---- MFMA roles: waves 2x2; wave tile 64 tok x 32 cols; frags 4m x 2n ----
    const int wm = w >> 1, wn = w & 1;
    const int lr = l & 15, lg = l >> 4;
    int ix[4], ig[2][2];
#pragma unroll
    for (int m = 0; m < 4; ++m) {
        int ra = wm * 64 + m * 16 + lr;
        ix[m] = ra * 32 + (lg ^ ((lr >> 1) & 3)) * 8;
    }
#pragma unroll
    for (int n = 0; n < 2; ++n) {
        int rb = wn * 32 + n * 16 + lr;
        ig[n][0] = rb * 32 + ((lg * 2)     ^ (lr & 7)) * 4;
        ig[n][1] = rb * 32 + ((lg * 2 + 1) ^ (lr & 7)) * 4;
    }

    const f32x4 Z4 = {0.f, 0.f, 0.f, 0.f};
    f32x4 aG[4][2], aU[4][2];
#pragma unroll
    for (int m = 0; m < 4; ++m)
#pragma unroll
        for (int n = 0; n < 2; ++n) { aG[m][n] = Z4; aU[m][n] = Z4; }

#define G1_MFMA(c) do { \
    bf16x8 xa[4], gg[2], uu[2]; \
    _Pragma("unroll") for (int m = 0; m < 4; ++m) xa[m] = *(const bf16x8*)&Xs[c][ix[m]]; \
    _Pragma("unroll") for (int n = 0; n < 2; ++n) { \
        f32x4 q0 = *(const f32x4*)&Gs[c][ig[n][0]]; \
        f32x4 q1 = *(const f32x4*)&Gs[c][ig[n][1]]; \
        gg[n] = cvt8(q0, q1); \
        f32x4 r0 = *(const f32x4*)&Us[c][ig[n][0]]; \
        f32x4 r1 = *(const f32x4*)&Us[c][ig[n][1]]; \
        uu[n] = cvt8(r0, r1); } \
    _Pragma("unroll") for (int m = 0; m < 4; ++m) \
    _Pragma("unroll") for (int n = 0; n < 2; ++n) { \
        aG[m][n] = __builtin_amdgcn_mfma_f32_16x16x32_bf16(xa[m], gg[n], aG[m][n], 0, 0, 0); \
        aU[m][n] = __builtin_amdgcn_mfma_f32_16x16x32_bf16(xa[m], uu[n], aU[m][n], 0, 0, 0); } \
    } while (0)

    const int NT = H_DIM / KC;                 // 64
    G1_ISSUE(0, 0);
    G1_ISSUE(1, 1);
    int cur = 0;
    for (int t = 0; t < NT - 1; ++t) {
        VM_WAIT(6);                            // K-step t landed (6 newer stay in flight)
        SBAR();                                // all waves' t data landed
        G1_MFMA(cur);
        if (t + 2 < NT) {
            LGKM0();
            SBAR();                            // all waves done reading buf cur
            G1_ISSUE(cur, t + 2);              // safe overwrite; 2 phases to land
        }
        cur ^= 1;
    }
    VM_WAIT(0);
    SBAR();
    G1_MFMA(cur);
#undef G1_ISSUE
#undef G1_MFMA

    // epilogue: clamp + silu(g)*u -> act bf16
#pragma unroll
    for (int m = 0; m < 4; ++m)
#pragma unroll
        for (int n = 0; n < 2; ++n) {
            int col = i0 + wn * 32 + n * 16 + lr;
            int rbase = row0 + wm * 64 + m * 16 + lg * 4;
#pragma unroll
            for (int q = 0; q < 4; ++q) {
                float g = fminf(aG[m][n][q], SWIGLU_LIMIT);
                float u = fminf(fmaxf(aU[m][n][q], -SWIGLU_LIMIT), SWIGLU_LIMIT);
                float s = 1.f / (1.f + __expf(-g));
                act[(size_t)(rbase + q) * I_DIM + col] = f2bf(g * s * u);
            }
        }
}

// ---------------- GEMM2: all-gload_lds, counted-vmcnt pipeline ----------------
__global__ __launch_bounds__(256, 4) void gemm2_scatter(
    const u16* __restrict__ act, const float* __restrict__ w2,
    const int* __restrict__ A_tok, const float* __restrict__ A_w,
    const int* __restrict__ tile_e, const int* __restrict__ tile_r0,
    float* __restrict__ out)
{
    int b = blockIdx.x;
    int id = (b & 7) * 192 + (b >> 3);         // 1536 = 8*192
    int tile = id % MAX_TILES;
    int y = id / MAX_TILES;                    // 0..31
    int e = tile_e[tile];
    if (e < 0) return;
    int row0 = tile_r0[tile];
    int h0 = y * 64;
    int tid = threadIdx.x;

    __shared__ u16  As[2][4096];   // 128 x 32 bf16
    __shared__ float Bs[2][2048];  // 64 x 32 fp32

    const int l = tid & 63, w = tid >> 6;

    const u16* sA[2]; int dA[2];
#pragma unroll
    for (int j = 0; j < 2; ++j) {
        int row = w * 32 + j * 16 + (l >> 2);
        int sg = (l & 3) ^ ((l >> 3) & 3);
        sA[j] = act + (size_t)(row0 + row) * I_DIM + sg * 8;
        dA[j] = (w * 32 + j * 16) * 32;
    }
    const float* sB[2]; int dB[2];
#pragma unroll
    for (int j = 0; j < 2; ++j) {
        int row = w * 16 + j * 8 + (l >> 3);
        int sg = (l & 7) ^ (l >> 3);
        sB[j] = w2 + ((size_t)e * H_DIM + h0 + row) * I_DIM + sg * 4;
        dB[j] = (w * 16 + j * 8) * 32;
    }

#define G2_ISSUE(bb, t) do { int ko = (t) * KC; \
    gload16(sA[0] + ko, &As[bb][dA[0]]);  gload16(sA[1] + ko, &As[bb][dA[1]]); \
    gload16f(sB[0] + ko, &Bs[bb][dB[0]]); gload16f(sB[1] + ko, &Bs[bb][dB[1]]); \
    SCHED0(); } while (0)

    const int wm = w >> 1, wn = w & 1;
    const int lr = l & 15, lg = l >> 4;
    int ix[4], ig[2][2];
#pragma unroll
    for (int m = 0; m < 4; ++m) {
        int ra = wm * 64 + m * 16 + lr;
        ix[m] = ra * 32 + (lg ^ ((lr >> 1) & 3)) * 8;
    }
#pragma unroll
    for (int n = 0; n < 2; ++n) {
        int rb = wn * 32 + n * 16 + lr;
        ig[n][0] = rb * 32 + ((lg * 2)     ^ (lr & 7)) * 4;
        ig[n][1] = rb * 32 + ((lg * 2 + 1) ^ (lr & 7)) * 4;
    }

    const f32x4 Z4 = {0.f, 0.f, 0.f, 0.f};
    f32x4 acc[4][2];
#pragma unroll
    for (int m = 0; m < 4; ++m)
#pragma unroll
        for (int n = 0; n < 2; ++n) acc[m][n] = Z4;

#define G2_MFMA(c) do { \
    bf16x8 xa[4], bb2[2]; \
    _Pragma("unroll") for (int m = 0; m < 4; ++m) xa[m] = *(const bf16x8*)&As[c][ix[m]]; \
    _Pragma("unroll") for (int n = 0; n < 2; ++n) { \
        f32x4 q0 = *(const f32x4*)&Bs[c][ig[n][0]]; \
        f32x4 q1 = *(const f32x4*)&Bs[c][ig[n][1]]; \
        bb2[n] = cvt8(q0, q1); } \
    _Pragma("unroll") for (int m = 0; m < 4; ++m) \
    _Pragma("unroll") for (int n = 0; n < 2; ++n) \
        acc[m][n] = __builtin_amdgcn_mfma_f32_16x16x32_bf16(xa[m], bb2[n], acc[m][n], 0, 0, 0); \
    } while (0)

    const int NT = I_DIM / KC;                 // 16
    G2_ISSUE(0, 0);
    G2_ISSUE(1, 1);
    int cur = 0;
    for (int t = 0; t < NT - 1; ++t) {
        VM_WAIT(4);
        SBAR();
        G2_MFMA(cur);
        if (t + 2 < NT) {
            LGKM0();
            SBAR();
            G2_ISSUE(cur, t + 2);
        }
        cur ^= 1;
    }
    VM_WAIT(0);
    SBAR();
    G2_MFMA(cur);
#undef G2_ISSUE
#undef G2_MFMA

    // epilogue: per-slot combine weight from global (no LDS)
#pragma unroll
    for (int m = 0; m < 4; ++m)
#pragma unroll
        for (int n = 0; n < 2; ++n) {
            int col = h0 + wn * 32 + n * 16 + lr;
            int sbase = wm * 64 + m * 16 + lg * 4;
#pragma unroll
            for (int q = 0; q < 4; ++q) {
                int slot = row0 + sbase + q;
                int tok = A_tok[slot];
                if (tok >= 0)
                    atomicAdd(&out[(size_t)tok * H_DIM + col], acc[m][n][q] * A_w[slot]);
            }
        }
}

extern "C" void kernel_launch(void* const* d_in, const int* in_sizes, int n_in,
                              void* d_out, int out_size, void* d_ws, size_t ws_size,
                              hipStream_t stream) {
    const float* hs   = (const float*)d_in[0];
    const float* gw   = (const float*)d_in[1];
    const float* bias = (const float*)d_in[2];
    const float* w13  = (const float*)d_in[3];
    const float* w2   = (const float*)d_in[4];
    float* out = (float*)d_out;

    char* ws = (char*)d_ws;
    int*   cnt      = (int*)(ws + 0);          // 64 B
    int*   tile_e   = (int*)(ws + 64);         // 192 B
    int*   tile_r0  = (int*)(ws + 320);        // 192 B (region to 1024)
    int*   tok_list = (int*)(ws + 1024);       // 131072 -> 132096
    float* w_list   = (float*)(ws + 132096);   // 131072 -> 263168
    int*   A_tok    = (int*)(ws + 263168);     // 24576  -> 287744
    float* A_w      = (float*)(ws + 287744);   // 24576  -> 312320
    u16*   act      = (u16*)(ws + 315392);     // 6291456 -> 6606848
    u16*   hs_bf    = (u16*)(ws + 6606848);    // 8388608 -> ~15 MB

    hipMemsetAsync(d_out, 0, (size_t)T_TOK * H_DIM * sizeof(float), stream);
    hipMemsetAsync(cnt, 0, 64, stream);

    router_kernel<<<T_TOK / 4, 256, 0, stream>>>(hs, gw, bias, cnt, tok_list, w_list, hs_bf);
    scatter_build<<<(E_EXP * T_TOK) / 256, 256, 0, stream>>>(cnt, tok_list, w_list, A_tok, A_w, tile_e, tile_r0);

    gemm1_act<<<MAX_TILES * 8, 256, 0, stream>>>(hs_bf, w13, A_tok, tile_e, tile_r0, act);
    gemm2_scatter<<<MAX_TILES * 32, 256, 0, stream>>>(act, w2, A_tok, A_w, tile_e, tile_r0, out);
}